// Round 1
// baseline (734.362 us; speedup 1.0000x reference)
//
#include <hip/hip_runtime.h>
#include <hip/hip_bf16.h>

// Problem dims
#define V_ 50000
#define E_ 300
#define H_ 800
#define K_ 128
#define B_ 131072

typedef float  f32x4 __attribute__((ext_vector_type(4)));
typedef float  f32x2 __attribute__((ext_vector_type(2)));
typedef int    i32x4 __attribute__((ext_vector_type(4)));
typedef unsigned int u32x2 __attribute__((ext_vector_type(2)));
typedef __bf16 bf16x8 __attribute__((ext_vector_type(8)));

#define LOG2E 1.4426950408889634f

// ---------------- ws layout (bytes) ----------------
static constexpr size_t OFF_ETB    = 0;                                   // [50048][128] f32
static constexpr size_t SZ_ETB     = (size_t)50048 * 128 * 4;             // 25,624,576
static constexpr size_t OFF_COLSUM = SZ_ETB;                              // 128 f32 (+pad)
static constexpr size_t OFF_PART   = OFF_COLSUM + 512;                    // partial[0]=loss, [1]=kld
static constexpr size_t OFF_RHOP   = OFF_COLSUM + 1024;                   // 3128 rowfrags x 10 ks x 1KB
static constexpr size_t SZ_RHOP    = (size_t)3128 * 10 * 1024;            // 32,030,720
static constexpr size_t OFF_Q1P    = OFF_RHOP + SZ_RHOP;                  // 50x10 frags
static constexpr size_t OFF_Q2P    = OFF_Q1P + (size_t)500 * 1024;        // 50x25 frags
static constexpr size_t OFF_HEADP  = OFF_Q2P + (size_t)1250 * 1024;       // 16x25 frags (mu strips 0-7, ls 8-15)
static constexpr size_t OFF_ALP    = OFF_HEADP + (size_t)400 * 1024;      // 8x10 frags

static __device__ __forceinline__ f32x4 mfma_bf16(i32x4 a, i32x4 b, f32x4 c) {
  return __builtin_amdgcn_mfma_f32_16x16x32_bf16(
      __builtin_bit_cast(bf16x8, a), __builtin_bit_cast(bf16x8, b), c, 0, 0, 0);
}

static __device__ __forceinline__ unsigned short f2bf(float x) {
  __hip_bfloat16 h = __float2bfloat16(x);
  return __builtin_bit_cast(unsigned short, h);
}

static __device__ __forceinline__ float tanh_fast(float x) {
  float xc = fminf(10.f, fmaxf(-10.f, x));
  float e  = exp2f(xc * 2.8853900817779268f);  // exp(2x)
  return (e - 1.f) / (e + 1.f);
}

static __device__ __forceinline__ f32x4 fzero() {
  f32x4 z; z.x = 0.f; z.y = 0.f; z.z = 0.f; z.w = 0.f; return z;
}

// ---------- pack A-side (rho): frag(rowfrag rfg, ks): lane l, j -> A[rfg*16 + (l&15)][ks*32 + (l>>4)*8 + j]
__global__ void pack_a_kernel(const float* __restrict__ A, int M, int Kdim, int nks,
                              unsigned short* __restrict__ dst) {
  __shared__ float tile[16][33];
  int b = blockIdx.x;
  int rfg = b / nks, ks = b % nks;
  int l = threadIdx.x;
  int rbase = rfg * 16, kbase = ks * 32;
  int rl = l >> 2, coff = (l & 3) * 8;
  int row = rbase + rl;
#pragma unroll
  for (int i = 0; i < 8; ++i) {
    int k = kbase + coff + i;
    float v = (row < M && k < Kdim) ? A[(size_t)row * Kdim + k] : 0.f;
    tile[rl][coff + i] = v;
  }
  __syncthreads();
  unsigned int out[4];
#pragma unroll
  for (int p = 0; p < 4; ++p) {
    float lo = tile[l & 15][(l >> 4) * 8 + 2 * p];
    float hi = tile[l & 15][(l >> 4) * 8 + 2 * p + 1];
    out[p] = (unsigned int)f2bf(lo) | ((unsigned int)f2bf(hi) << 16);
  }
  *reinterpret_cast<i32x4*>(dst + (size_t)b * 512 + l * 8) =
      *reinterpret_cast<i32x4*>(out);
}

// ---------- pack B-side (weights [Kdim][N] row-major): frag(strip sl, ks): lane l, j -> W[ks*32 + (l>>4)*8 + j][nbase0 + sl*16 + (l&15)]
__global__ void pack_b_kernel(const float* __restrict__ W, int Kdim, int N, int nks,
                              int nbase0, unsigned short* __restrict__ dst) {
  __shared__ float tile[32][17];
  int b = blockIdx.x;
  int sl = b / nks, ks = b % nks;
  int l = threadIdx.x;
  int kbase = ks * 32, nbase = nbase0 + sl * 16;
  int kl = l >> 1, noff = (l & 1) * 8;
#pragma unroll
  for (int i = 0; i < 8; ++i) {
    int k = kbase + kl;
    float v = (k < Kdim) ? W[(size_t)k * N + nbase + noff + i] : 0.f;
    tile[kl][noff + i] = v;
  }
  __syncthreads();
  unsigned int out[4];
#pragma unroll
  for (int p = 0; p < 4; ++p) {
    float lo = tile[(l >> 4) * 8 + 2 * p][l & 15];
    float hi = tile[(l >> 4) * 8 + 2 * p + 1][l & 15];
    out[p] = (unsigned int)f2bf(lo) | ((unsigned int)f2bf(hi) << 16);
  }
  *reinterpret_cast<i32x4*>(dst + (size_t)b * 512 + l * 8) =
      *reinterpret_cast<i32x4*>(out);
}

// ---------- tb kernel: Etb = exp(rho @ alphas), colsum over vocab ----------
__global__ __launch_bounds__(512) void tb_kernel(
    const unsigned short* __restrict__ rhop, const unsigned short* __restrict__ alphap,
    float* __restrict__ Etb, float* __restrict__ colsum) {
  int tid = threadIdx.x;
  int wid = tid >> 6, l = tid & 63;
  int tile = blockIdx.x;
  const i32x4* rp = reinterpret_cast<const i32x4*>(rhop);
  const i32x4* ap = reinterpret_cast<const i32x4*>(alphap);
  f32x4 acc[4];
#pragma unroll
  for (int rf = 0; rf < 4; ++rf) acc[rf] = fzero();
  for (int ks = 0; ks < 10; ++ks) {
    i32x4 bfrag = ap[(size_t)(wid * 10 + ks) * 64 + l];
    i32x4 afr[4];
#pragma unroll
    for (int rf = 0; rf < 4; ++rf)
      afr[rf] = rp[((size_t)(tile * 4 + rf) * 10 + ks) * 64 + l];
#pragma unroll
    for (int rf = 0; rf < 4; ++rf) acc[rf] = mfma_bf16(afr[rf], bfrag, acc[rf]);
  }
  float colpart = 0.f;
  int colbase = wid * 16 + (l & 15);
#pragma unroll
  for (int rf = 0; rf < 4; ++rf) {
#pragma unroll
    for (int r = 0; r < 4; ++r) {
      int row = tile * 64 + rf * 16 + (l >> 4) * 4 + r;
      if (row < V_) {
        float e = exp2f(acc[rf][r] * LOG2E);
        Etb[(size_t)row * 128 + colbase] = e;
        colpart += e;
      }
    }
  }
  colpart += __shfl_xor(colpart, 16);
  colpart += __shfl_xor(colpart, 32);
  if (l < 16) atomicAdd(&colsum[wid * 16 + l], colpart);
}

// ---------- fused main kernel: 64 rows/block, 8 waves ----------
__global__ __launch_bounds__(512, 2) void fused_kernel(
    const int* __restrict__ bi_idx, const float* __restrict__ biterms,
    const float* __restrict__ q1b, const float* __restrict__ q2b,
    const float* __restrict__ mub, const float* __restrict__ lsb,
    const unsigned short* __restrict__ q1p, const unsigned short* __restrict__ q2p,
    const unsigned short* __restrict__ headp,
    const float* __restrict__ Etb, const float* __restrict__ colsum,
    float* __restrict__ partial) {
  __shared__ __align__(16) unsigned short sH[64 * 808];   // 103,424 B
  __shared__ __align__(16) unsigned short sA[64 * 328];   // 41,984 B (aliased as sMu f32 [64][132] later)
  __shared__ float sInv[128];

  int tid = threadIdx.x, wid = tid >> 6, l = tid & 63;
  int row0 = blockIdx.x * 64;

  if (tid < 128) { float c = colsum[tid]; sInv[tid] = 1.f / (c * c); }

  // stage biterms -> sA (bf16), K padded 300->320 with zeros
  for (int idx = tid; idx < 64 * 75; idx += 512) {
    int r = idx / 75, c4 = idx % 75;
    f32x4 v = *reinterpret_cast<const f32x4*>(biterms + (size_t)(row0 + r) * 300 + c4 * 4);
    unsigned int w0 = (unsigned int)f2bf(v.x) | ((unsigned int)f2bf(v.y) << 16);
    unsigned int w1 = (unsigned int)f2bf(v.z) | ((unsigned int)f2bf(v.w) << 16);
    u32x2 w; w.x = w0; w.y = w1;
    *reinterpret_cast<u32x2*>(&sA[r * 328 + c4 * 4]) = w;
  }
  for (int idx = tid; idx < 64 * 10; idx += 512) {
    int r = idx / 10, c = idx % 10;
    *reinterpret_cast<unsigned int*>(&sA[r * 328 + 300 + c * 2]) = 0u;
  }
  __syncthreads();

  const i32x4* q1pv = reinterpret_cast<const i32x4*>(q1p);
  const i32x4* q2pv = reinterpret_cast<const i32x4*>(q2p);
  const i32x4* hpv  = reinterpret_cast<const i32x4*>(headp);

  // ---- GEMM1: h1 = tanh(sA @ q1 + b1) -> sH ----
  for (int g = wid; g < 25; g += 8) {
    int s0 = 2 * g;
    f32x4 acc[2][4];
#pragma unroll
    for (int t = 0; t < 2; ++t)
#pragma unroll
      for (int rf = 0; rf < 4; ++rf) acc[t][rf] = fzero();
    for (int ks = 0; ks < 10; ++ks) {
      i32x4 b0 = q1pv[(size_t)(s0 * 10 + ks) * 64 + l];
      i32x4 b1 = q1pv[(size_t)((s0 + 1) * 10 + ks) * 64 + l];
      i32x4 a[4];
#pragma unroll
      for (int rf = 0; rf < 4; ++rf)
        a[rf] = *reinterpret_cast<const i32x4*>(
            &sA[(rf * 16 + (l & 15)) * 328 + ks * 32 + (l >> 4) * 8]);
#pragma unroll
      for (int rf = 0; rf < 4; ++rf) {
        acc[0][rf] = mfma_bf16(a[rf], b0, acc[0][rf]);
        acc[1][rf] = mfma_bf16(a[rf], b1, acc[1][rf]);
      }
    }
#pragma unroll
    for (int t = 0; t < 2; ++t) {
      int col = (s0 + t) * 16 + (l & 15);
      float bias = q1b[col];
#pragma unroll
      for (int rf = 0; rf < 4; ++rf)
#pragma unroll
        for (int r = 0; r < 4; ++r) {
          int row = rf * 16 + (l >> 4) * 4 + r;
          sH[row * 808 + col] = f2bf(tanh_fast(acc[t][rf][r] + bias));
        }
    }
  }
  __syncthreads();

  // ---- GEMM2: h2 = tanh(sH @ q2 + b2) -> sH (register-resident until barrier) ----
  f32x4 acc2[7][4];
#pragma unroll
  for (int si = 0; si < 7; ++si)
#pragma unroll
    for (int rf = 0; rf < 4; ++rf) acc2[si][rf] = fzero();
  for (int ks = 0; ks < 25; ++ks) {
    i32x4 a[4];
#pragma unroll
    for (int rf = 0; rf < 4; ++rf)
      a[rf] = *reinterpret_cast<const i32x4*>(
          &sH[(rf * 16 + (l & 15)) * 808 + ks * 32 + (l >> 4) * 8]);
    i32x4 bfr[7];
#pragma unroll
    for (int si = 0; si < 7; ++si) {
      int s = wid + 8 * si;
      if (s < 50) bfr[si] = q2pv[(size_t)(s * 25 + ks) * 64 + l];
    }
#pragma unroll
    for (int si = 0; si < 7; ++si) {
      int s = wid + 8 * si;
      if (s < 50) {
#pragma unroll
        for (int rf = 0; rf < 4; ++rf) acc2[si][rf] = mfma_bf16(a[rf], bfr[si], acc2[si][rf]);
      }
    }
  }
  __syncthreads();   // all reads of old sH done
#pragma unroll
  for (int si = 0; si < 7; ++si) {
    int s = wid + 8 * si;
    if (s < 50) {
      int col = s * 16 + (l & 15);
      float bias = q2b[col];
#pragma unroll
      for (int rf = 0; rf < 4; ++rf)
#pragma unroll
        for (int r = 0; r < 4; ++r) {
          int row = rf * 16 + (l >> 4) * 4 + r;
          sH[row * 808 + col] = f2bf(tanh_fast(acc2[si][rf][r] + bias));
        }
    }
  }
  __syncthreads();

  // ---- GEMM3: mu (strip wid) and logsigma (strip wid+8); kld partials; mu -> sMu ----
  float* sMu = reinterpret_cast<float*>(sA);
  f32x4 acc3[2][4];
#pragma unroll
  for (int t = 0; t < 2; ++t)
#pragma unroll
    for (int rf = 0; rf < 4; ++rf) acc3[t][rf] = fzero();
  for (int ks = 0; ks < 25; ++ks) {
    i32x4 a[4];
#pragma unroll
    for (int rf = 0; rf < 4; ++rf)
      a[rf] = *reinterpret_cast<const i32x4*>(
          &sH[(rf * 16 + (l & 15)) * 808 + ks * 32 + (l >> 4) * 8]);
    i32x4 b0 = hpv[(size_t)(wid * 25 + ks) * 64 + l];
    i32x4 b1 = hpv[(size_t)((wid + 8) * 25 + ks) * 64 + l];
#pragma unroll
    for (int rf = 0; rf < 4; ++rf) {
      acc3[0][rf] = mfma_bf16(a[rf], b0, acc3[0][rf]);
      acc3[1][rf] = mfma_bf16(a[rf], b1, acc3[1][rf]);
    }
  }
  {
    int col = wid * 16 + (l & 15);
    float mb = mub[col], lb = lsb[col];
    float kldpart = 0.f;
#pragma unroll
    for (int rf = 0; rf < 4; ++rf)
#pragma unroll
      for (int r = 0; r < 4; ++r) {
        int row = rf * 16 + (l >> 4) * 4 + r;
        float m = acc3[0][rf][r] + mb;
        sMu[row * 132 + col] = m;
        kldpart -= m * m;
        float v = acc3[1][rf][r] + lb;
        kldpart += 1.f + v - exp2f(v * LOG2E);
      }
    kldpart += __shfl_xor(kldpart, 1);
    kldpart += __shfl_xor(kldpart, 2);
    kldpart += __shfl_xor(kldpart, 4);
    kldpart += __shfl_xor(kldpart, 8);
    kldpart += __shfl_xor(kldpart, 16);
    kldpart += __shfl_xor(kldpart, 32);
    if (l == 0) atomicAdd(&partial[1], kldpart);
  }
  __syncthreads();

  // ---- decode: softmax over mu row + gather dot ----
  const int2* bi2 = reinterpret_cast<const int2*>(bi_idx);
  float lsum = 0.f;
  for (int rr = 0; rr < 8; ++rr) {
    int r = wid * 8 + rr;
    int2 bi = bi2[row0 + r];
    f32x2 m2 = *reinterpret_cast<const f32x2*>(&sMu[r * 132 + 2 * l]);
    float mx = fmaxf(m2.x, m2.y);
    mx = fmaxf(mx, __shfl_xor(mx, 1));
    mx = fmaxf(mx, __shfl_xor(mx, 2));
    mx = fmaxf(mx, __shfl_xor(mx, 4));
    mx = fmaxf(mx, __shfl_xor(mx, 8));
    mx = fmaxf(mx, __shfl_xor(mx, 16));
    mx = fmaxf(mx, __shfl_xor(mx, 32));
    float t0 = exp2f((m2.x - mx) * LOG2E);
    float t1 = exp2f((m2.y - mx) * LOG2E);
    float den = t0 + t1;
    den += __shfl_xor(den, 1);
    den += __shfl_xor(den, 2);
    den += __shfl_xor(den, 4);
    den += __shfl_xor(den, 8);
    den += __shfl_xor(den, 16);
    den += __shfl_xor(den, 32);
    f32x2 e0 = *reinterpret_cast<const f32x2*>(&Etb[(size_t)bi.x * 128 + 2 * l]);
    f32x2 e1 = *reinterpret_cast<const f32x2*>(&Etb[(size_t)bi.y * 128 + 2 * l]);
    f32x2 iv = *reinterpret_cast<const f32x2*>(&sInv[2 * l]);
    float p = t0 * t0 * e0.x * e1.x * iv.x + t1 * t1 * e0.y * e1.y * iv.y;
    p += __shfl_xor(p, 1);
    p += __shfl_xor(p, 2);
    p += __shfl_xor(p, 4);
    p += __shfl_xor(p, 8);
    p += __shfl_xor(p, 16);
    p += __shfl_xor(p, 32);
    float res = p / (den * den);
    lsum += logf(res + 1e-6f);
  }
  if (l == 0) atomicAdd(&partial[0], lsum);
}

__global__ void finalize_kernel(const float* __restrict__ partial, float* __restrict__ out) {
  if (threadIdx.x == 0) {
    out[0] = partial[0] / (float)B_;
    out[1] = -0.5f * partial[1] / (float)B_;
  }
}

extern "C" void kernel_launch(void* const* d_in, const int* in_sizes, int n_in,
                              void* d_out, int out_size, void* d_ws, size_t ws_size,
                              hipStream_t stream) {
  const int*   bi_idx   = (const int*)d_in[0];
  const float* biterms  = (const float*)d_in[1];
  const float* rho      = (const float*)d_in[2];
  const float* alphas_W = (const float*)d_in[3];
  const float* q1_W     = (const float*)d_in[4];
  const float* q1_b     = (const float*)d_in[5];
  const float* q2_W     = (const float*)d_in[6];
  const float* q2_b     = (const float*)d_in[7];
  const float* mu_W     = (const float*)d_in[8];
  const float* mu_b     = (const float*)d_in[9];
  const float* ls_W     = (const float*)d_in[10];
  const float* ls_b     = (const float*)d_in[11];

  char* ws = (char*)d_ws;
  float* Etb     = (float*)(ws + OFF_ETB);
  float* colsum  = (float*)(ws + OFF_COLSUM);
  float* partial = (float*)(ws + OFF_PART);
  unsigned short* rhop  = (unsigned short*)(ws + OFF_RHOP);
  unsigned short* q1p   = (unsigned short*)(ws + OFF_Q1P);
  unsigned short* q2p   = (unsigned short*)(ws + OFF_Q2P);
  unsigned short* headp = (unsigned short*)(ws + OFF_HEADP);
  unsigned short* alphap= (unsigned short*)(ws + OFF_ALP);

  hipMemsetAsync(ws + OFF_COLSUM, 0, 1024, stream);  // colsum + partials

  pack_a_kernel<<<3128 * 10, 64, 0, stream>>>(rho, V_, E_, 10, rhop);
  pack_b_kernel<<<8 * 10, 64, 0, stream>>>(alphas_W, E_, K_, 10, 0, alphap);
  pack_b_kernel<<<50 * 10, 64, 0, stream>>>(q1_W, E_, H_, 10, 0, q1p);
  pack_b_kernel<<<50 * 25, 64, 0, stream>>>(q2_W, H_, H_, 25, 0, q2p);
  pack_b_kernel<<<8 * 25, 64, 0, stream>>>(mu_W, H_, K_, 25, 0, headp);
  pack_b_kernel<<<8 * 25, 64, 0, stream>>>(ls_W, H_, K_, 25, 0, headp + (size_t)200 * 512);

  tb_kernel<<<782, 512, 0, stream>>>(rhop, alphap, Etb, colsum);

  fused_kernel<<<B_ / 64, 512, 0, stream>>>(bi_idx, biterms, q1_b, q2_b, mu_b, ls_b,
                                            q1p, q2p, headp, Etb, colsum, partial);

  finalize_kernel<<<1, 64, 0, stream>>>(partial, (float*)d_out);
}